// Round 9
// baseline (355.553 us; speedup 1.0000x reference)
//
#include <hip/hip_runtime.h>
#include <cstddef>

#define NN   30000
#define NNP  30016          /* NN ints rounded to 256B alloc granularity */
#define NE   240000
#define D1   512
#define D2   128
#define NCLS 20
#define NB   ((NN + 255) / 256)   /* 118 scan blocks */

typedef __attribute__((ext_vector_type(8))) short short8;
typedef __attribute__((ext_vector_type(4))) float f32x4;

__device__ __forceinline__ unsigned short f2b(float f) {
  union { float f; unsigned int u; } c; c.f = f;
  unsigned int r = (c.u + 0x7fff + ((c.u >> 16) & 1)) >> 16;  // RNE
  return (unsigned short)r;
}
__device__ __forceinline__ float b2f(unsigned short u) {
  union { unsigned int u; float f; } c; c.u = (unsigned int)u << 16;
  return c.f;
}
constexpr int ilog2(int x) { int s = 0; while ((1 << s) < x) s++; return s; }

// ---------------------------------------------------------------- fused init
#define INIT_TOT 1048048
__global__ __launch_bounds__(256) void k_init(
    const float* __restrict__ x,
    const float* __restrict__ Wl1, const float* __restrict__ Wr1,
    const float* __restrict__ Wl2, const float* __restrict__ Wr2,
    int* __restrict__ zbase,
    unsigned short* __restrict__ xb,
    unsigned short* __restrict__ Wc1, unsigned short* __restrict__ Wc2) {
  int i = blockIdx.x * 256 + threadIdx.x;
  if (i < 22512) { ((int4*)zbase)[i] = make_int4(0, 0, 0, 0); return; }
  const float* in; unsigned short* outp; int off;
  if      (i <  982512) { in = x;   outp = xb;          off = i -   22512; }
  else if (i <  998896) { in = Wl1; outp = Wc1;         off = i -  982512; }
  else if (i < 1015280) { in = Wr1; outp = Wc1 + 65536; off = i -  998896; }
  else if (i < 1031664) { in = Wl2; outp = Wc2;         off = i - 1015280; }
  else if (i < 1048048) { in = Wr2; outp = Wc2 + 65536; off = i - 1031664; }
  else return;
  float4 v = ((const float4*)in)[off];
  ushort4 o;
  o.x = f2b(v.x); o.y = f2b(v.y); o.z = f2b(v.z); o.w = f2b(v.w);
  ((ushort4*)outp)[off] = o;
}

__global__ __launch_bounds__(256) void k_deg(const int* __restrict__ dst,
                                             const float* __restrict__ eattr,
                                             int* __restrict__ cnti,
                                             float* __restrict__ lsum) {
  int e = blockIdx.x * 256 + threadIdx.x;
  if (e < NE) {
    int d = dst[e];
    atomicAdd(&cnti[d], 1);
    atomicAdd(&lsum[d], eattr[e]);
  }
}

// block-scan of degrees + self-loop attr (la) in one pass
__global__ __launch_bounds__(256) void k_scan1(const int* __restrict__ cnti,
                                               const float* __restrict__ lsum,
                                               int* __restrict__ rowoff,
                                               int* __restrict__ bsum,
                                               float* __restrict__ la) {
  int i = blockIdx.x * 256 + threadIdx.x;
  int c = (i < NN) ? cnti[i] : 0;
  if (i < NN) la[i] = lsum[i] / fmaxf((float)c, 1.0f);
  int lane = threadIdx.x & 63, w = threadIdx.x >> 6;
  int v = c;
#pragma unroll
  for (int o = 1; o < 64; o <<= 1) { int t = __shfl_up(v, o); if (lane >= o) v += t; }
  __shared__ int ws[4];
  if (lane == 63) ws[w] = v;
  __syncthreads();
  int add = 0;
  for (int k = 0; k < w; k++) add += ws[k];
  v += add;
  if (i < NN) rowoff[i] = v - c;
  if (threadIdx.x == 255) bsum[blockIdx.x] = v;
}

__global__ __launch_bounds__(128) void k_scan2(const int* __restrict__ bsum,
                                               int* __restrict__ boff) {
  __shared__ int s[128];
  int t = threadIdx.x;
  int orig = (t < NB) ? bsum[t] : 0;
  s[t] = orig;
  __syncthreads();
  for (int o = 1; o < 128; o <<= 1) {
    int v = (t >= o) ? s[t - o] : 0;
    __syncthreads();
    s[t] += v;
    __syncthreads();
  }
  boff[t] = s[t] - orig;
}

__global__ __launch_bounds__(256) void k_fill(const int* __restrict__ src,
                                              const int* __restrict__ dst,
                                              const float* __restrict__ eattr,
                                              const int* __restrict__ rowoff,
                                              const int* __restrict__ boff,
                                              int* __restrict__ cursor,
                                              int2* __restrict__ se) {
  int e = blockIdx.x * 256 + threadIdx.x;
  if (e < NE) {
    int d = dst[e];
    int pos = rowoff[d] + boff[d >> 8] + atomicAdd(&cursor[d], 1);
    se[pos] = make_int2(src[e], __float_as_int(eattr[e]));
  }
}

// ---------------------------------------------------------------- bf16 MFMA GEMM
// [Cl|Cr][m,n] = sum_k A[m,k]*W[n,k] + bias, W = [Wl;Wr] concat in n; split out.
// R7 structure (both operands staged, BK=32); BN templated for occupancy.
template <int BN, int NT>   // NT = BN/32 n-tiles per wave
__global__ __launch_bounds__(256) void gemm_mfma(
    const unsigned short* __restrict__ A, const unsigned short* __restrict__ W,
    const float* __restrict__ bl, const float* __restrict__ br, int Nhalf,
    unsigned short* __restrict__ Cl, unsigned short* __restrict__ Cr,
    int M, int N, int K) {
  constexpr int BM = 128, BK = 32, LDK = BK + 8;
  __shared__ __align__(16) unsigned short As[BM * LDK];
  __shared__ __align__(16) unsigned short Bs[BN * LDK];
  const int bm = blockIdx.y * BM;
  const int bn = blockIdx.x * BN;
  const int tid = threadIdx.x;
  const int wid = tid >> 6, lane = tid & 63;
  const int wm = (wid >> 1) * 64;
  const int wn = (wid & 1) * (NT * 16);
  const int l16 = lane & 15, lq = lane >> 4;
  const int r0 = tid >> 2;
  const int ks = (tid & 3) * 8;

  f32x4 acc[4][NT];
#pragma unroll
  for (int i = 0; i < 4; ++i)
#pragma unroll
    for (int j = 0; j < NT; ++j) acc[i][j] = (f32x4){0.f, 0.f, 0.f, 0.f};

  for (int k0 = 0; k0 < K; k0 += BK) {
#pragma unroll
    for (int p = 0; p < BM / 64; ++p) {
      int r = r0 + p * 64;
      int gm = bm + r;
      uint4 v = {0u, 0u, 0u, 0u};
      if (gm < M) v = *(const uint4*)(A + (size_t)gm * K + k0 + ks);
      *(uint4*)&As[r * LDK + ks] = v;
    }
#pragma unroll
    for (int p = 0; p < BN / 64; ++p) {
      int r = r0 + p * 64;
      int gn = bn + r;
      uint4 v = {0u, 0u, 0u, 0u};
      if (gn < N) v = *(const uint4*)(W + (size_t)gn * K + k0 + ks);
      *(uint4*)&Bs[r * LDK + ks] = v;
    }
    __syncthreads();
    short8 af[4], bfr[NT];
#pragma unroll
    for (int mt = 0; mt < 4; ++mt)
      af[mt] = *(const short8*)&As[(wm + mt * 16 + l16) * LDK + lq * 8];
#pragma unroll
    for (int nt = 0; nt < NT; ++nt)
      bfr[nt] = *(const short8*)&Bs[(wn + nt * 16 + l16) * LDK + lq * 8];
#pragma unroll
    for (int mt = 0; mt < 4; ++mt)
#pragma unroll
      for (int nt = 0; nt < NT; ++nt)
        acc[mt][nt] = __builtin_amdgcn_mfma_f32_16x16x32_bf16(
            af[mt], bfr[nt], acc[mt][nt], 0, 0, 0);
    __syncthreads();
  }

#pragma unroll
  for (int mt = 0; mt < 4; ++mt)
#pragma unroll
    for (int nt = 0; nt < NT; ++nt) {
      int col = bn + wn + nt * 16 + l16;
      bool left = col < Nhalf;                 // uniform: 64-col strips
      int cc = left ? col : col - Nhalf;
      float b = left ? bl[cc] : br[cc];
      unsigned short* Cp = left ? Cl : Cr;
#pragma unroll
      for (int r = 0; r < 4; ++r) {
        int row = bm + wm + mt * 16 + lq * 4 + r;
        if (row < M) Cp[(size_t)row * Nhalf + cc] = f2b(acc[mt][nt][r] + b);
      }
    }
}

// ---------------------------------------------------------------- fused GATv2 aggregate
// Slot-parallel: each edge occupies LPE lanes (VEC=D/LPE channels/lane);
// S=64/LPE slots per wave process different edges concurrently, C chains deep.
// Per-edge butterfly = log2(LPE/2) stages shared by S edges; exp shared by
// slot lanes. End: slot-combine (shfl m=LPE..32) then in-slot RMS reduce.
// One wave per node, 4 nodes/block. wgt=0 masks overrun (incl. self-loop pad).
template <int D, int LPE, int C, bool DO_SILU, bool OBF, bool HEAD_GEMM>
__global__ __launch_bounds__(256) void k_gat_slot(
    const int2* __restrict__ se,
    const int* __restrict__ rowoff, const int* __restrict__ boff,
    const int* __restrict__ cnti, const float* __restrict__ la,
    const unsigned short* __restrict__ xl, const unsigned short* __restrict__ xr,
    const float* __restrict__ We, const float* __restrict__ att,
    const float* __restrict__ bias, const float* __restrict__ w_ln,
    const float* __restrict__ Wout,
    unsigned short* __restrict__ outb, float* __restrict__ outf) {
  constexpr int VEC = D / LPE;     // channels per lane
  constexpr int S = 64 / LPE;      // edge slots per wave
  constexpr int SSH = ilog2(LPE);
  typedef __attribute__((ext_vector_type(VEC))) unsigned short uvec;
  const int w = __builtin_amdgcn_readfirstlane(threadIdx.x) >> 6;  // SGPR wave id
  const int n = blockIdx.x * 4 + w;                                // SGPR node
  const int lane = threadIdx.x & 63;
  const int slot = lane >> SSH;
  const int lis = lane & (LPE - 1);
  const int c0 = lis * VEC;

  float xd[VEC], we[VEC], at[VEC], acc[VEC] = {};
  {
    uvec u = *(const uvec*)(xr + (size_t)n * D + c0);
#pragma unroll
    for (int k = 0; k < VEC; k++) {
      xd[k] = b2f(u[k]);
      we[k] = We[c0 + k];
      at[k] = att[c0 + k];
    }
  }

  const int start = rowoff[n] + boff[n >> 8];
  const int deg = cnti[n];
  const int total = deg + 1;                    // + self-loop
  const float lan = la[n];
  float denom = 0.f;

  for (int base = 0; base < total; base += S * C) {
    int s[C]; float ea[C], wgt[C];
    uvec u[C];
#pragma unroll
    for (int j = 0; j < C; j++) {
      int idx = base + j * S + slot;
      if (idx < deg) { int2 e = se[start + idx]; s[j] = e.x; ea[j] = __int_as_float(e.y); }
      else           { s[j] = n; ea[j] = lan; }
      wgt[j] = (idx < total) ? 1.f : 0.f;
    }
#pragma unroll
    for (int j = 0; j < C; j++)
      u[j] = *(const uvec*)(xl + (size_t)s[j] * D + c0);   // gathers in flight
    float xs[C][VEC];
    float p[C] = {};
#pragma unroll
    for (int k = 0; k < VEC; k++) {
#pragma unroll
      for (int j = 0; j < C; j++) {
        xs[j][k] = b2f(u[j][k]);
        float q = xs[j][k] + fmaf(ea[j], we[k], xd[k]);
        q = fmaxf(q, 0.2f * q);
        p[j] = fmaf(at[k], q, p[j]);
      }
    }
#pragma unroll
    for (int o = LPE / 4; o > 0; o >>= 1) {     // per-head butterfly (in-slot)
#pragma unroll
      for (int j = 0; j < C; j++) p[j] += __shfl_xor(p[j], o);
    }
    float pe[C];
#pragma unroll
    for (int j = 0; j < C; j++) {
      pe[j] = __expf(p[j]) * wgt[j];
      denom += pe[j];
    }
#pragma unroll
    for (int k = 0; k < VEC; k++) {
#pragma unroll
      for (int j = 0; j < C; j++)
        acc[k] = fmaf(pe[j], xs[j][k], acc[k]);
    }
  }

  // combine across slots (same channels+head live at lane ^ m)
#pragma unroll
  for (int m = LPE; m < 64; m <<= 1) {
    denom += __shfl_xor(denom, m);
#pragma unroll
    for (int k = 0; k < VEC; k++) acc[k] += __shfl_xor(acc[k], m);
  }

  float inv = 1.f / denom;                      // per-head value
  float vv[VEC], ss = 0.f;
#pragma unroll
  for (int k = 0; k < VEC; k++) {
    float v = fmaf(acc[k], inv, bias[c0 + k]);
    if (DO_SILU) v = v / (1.f + __expf(-v));
    vv[k] = v;
    ss += v * v;
  }
#pragma unroll
  for (int o = LPE / 2; o > 0; o >>= 1) ss += __shfl_xor(ss, o);  // in-slot: all D
  float rinv = rsqrtf(ss / (float)D + 1e-5f);

  __shared__ __align__(16) float hrow[4][D2];
  if (slot == 0) {
#pragma unroll
    for (int k = 0; k < VEC; k++) {
      float o = vv[k] * rinv * w_ln[c0 + k];
      if (OBF) outb[(size_t)n * D + c0 + k] = f2b(o);
      if (HEAD_GEMM) hrow[w][c0 + k] = o;
    }
  }
  if (HEAD_GEMM) {
    __syncthreads();                            // no early returns: NN % 4 == 0
    int t = threadIdx.x;
    if (t < 4 * NCLS) {
      int n4 = t / NCLS, c = t % NCLS;
      const float4* wr = (const float4*)(Wout + c * D2);
      const float4* hr = (const float4*)&hrow[n4][0];
      float sm = 0.f;
#pragma unroll
      for (int q = 0; q < D2 / 4; q++) {
        float4 a = hr[q], b = wr[q];
        sm += a.x * b.x + a.y * b.y + a.z * b.z + a.w * b.w;
      }
      outf[(size_t)(blockIdx.x * 4 + n4) * NCLS + c] = sm;
    }
  }
}

// ---------------------------------------------------------------- launch
extern "C" void kernel_launch(void* const* d_in, const int* in_sizes, int n_in,
                              void* d_out, int out_size, void* d_ws, size_t ws_size,
                              hipStream_t stream) {
  const float* x     = (const float*)d_in[0];
  const int*   ei    = (const int*)  d_in[1];
  const float* eattr = (const float*)d_in[2];
  const float* Wl1   = (const float*)d_in[3];
  const float* bl1   = (const float*)d_in[4];
  const float* Wr1   = (const float*)d_in[5];
  const float* br1   = (const float*)d_in[6];
  const float* We1   = (const float*)d_in[7];
  const float* att1  = (const float*)d_in[8];
  const float* bias1 = (const float*)d_in[9];
  const float* Wl2   = (const float*)d_in[10];
  const float* bl2   = (const float*)d_in[11];
  const float* Wr2   = (const float*)d_in[12];
  const float* br2   = (const float*)d_in[13];
  const float* We2   = (const float*)d_in[14];
  const float* att2  = (const float*)d_in[15];
  const float* bias2 = (const float*)d_in[16];
  const float* w_ln1 = (const float*)d_in[17];
  const float* w_ln3 = (const float*)d_in[18];
  const float* W_out = (const float*)d_in[19];
  float* out = (float*)d_out;
  (void)in_sizes; (void)n_in; (void)out_size; (void)ws_size;

  const int* src = ei;
  const int* dst = ei + NE;

  char* wsp = (char*)d_ws;
  auto alloc = [&](size_t nbytes) {
    char* ptr = wsp;
    wsp += ((nbytes + 255) / 256) * 256;
    return ptr;
  };
  int*   cnti   = (int*)  alloc((size_t)NN * 4);   // } contiguous (NNP ints each):
  int*   cursor = (int*)  alloc((size_t)NN * 4);   // } zeroed as 3*NNP ints in k_init
  float* lsum   = (float*)alloc((size_t)NN * 4);   // }
  float* la     = (float*)alloc((size_t)NN * 4);
  int*   rowoff = (int*)  alloc((size_t)NN * 4);
  int*   bsum   = (int*)  alloc(128 * 4);
  int*   boff   = (int*)  alloc(128 * 4);
  int2*  se     = (int2*) alloc((size_t)NE * 8);
  unsigned short* xb   = (unsigned short*)alloc((size_t)NN * D2 * 2);
  unsigned short* Wc1  = (unsigned short*)alloc((size_t)2 * D1 * D2 * 2);
  unsigned short* Wc2  = (unsigned short*)alloc((size_t)2 * D2 * D1 * 2);
  unsigned short* xl1  = (unsigned short*)alloc((size_t)NN * D1 * 2);  // gather table
  unsigned short* xr1  = (unsigned short*)alloc((size_t)NN * D1 * 2);
  unsigned short* h1b  = (unsigned short*)alloc((size_t)NN * D1 * 2);
  unsigned short* xl2  = (unsigned short*)alloc((size_t)NN * D2 * 2);
  unsigned short* xr2  = (unsigned short*)alloc((size_t)NN * D2 * 2);

  // --- fused init/cast + CSR build ---
  k_init<<<(INIT_TOT + 255) / 256, 256, 0, stream>>>(x, Wl1, Wr1, Wl2, Wr2,
                                                     cnti, xb, Wc1, Wc2);
  k_deg<<<(NE + 255) / 256, 256, 0, stream>>>(dst, eattr, cnti, lsum);
  k_scan1<<<NB, 256, 0, stream>>>(cnti, lsum, rowoff, bsum, la);
  k_scan2<<<1, 128, 0, stream>>>(bsum, boff);
  k_fill<<<(NE + 255) / 256, 256, 0, stream>>>(src, dst, eattr, rowoff, boff, cursor, se);

  const int GB = NN / 4;             // 4 nodes/block, 1 wave each (NN % 4 == 0)
  const int MB = (NN + 127) / 128;   // 235 row-tiles

  // --- layer 1: [xl1|xr1] = x @ [Wl1;Wr1]^T + [bl1;br1]  (split bf16 out) ---
  gemm_mfma<128, 4><<<dim3(2 * D1 / 128, MB), 256, 0, stream>>>(
      xb, Wc1, bl1, br1, D1, xl1, xr1, NN, 2 * D1, D2);
  k_gat_slot<D1, 32, 2, true, true, false><<<GB, 256, 0, stream>>>(
      se, rowoff, boff, cnti, la, xl1, xr1, We1, att1, bias1, w_ln1, nullptr, h1b, nullptr);

  // --- layer 2: [xl2|xr2] = h1 @ [Wl2;Wr2]^T + [bl2;br2]  (split bf16 out) ---
  gemm_mfma<64, 2><<<dim3(2 * D2 / 64, MB), 256, 0, stream>>>(
      h1b, Wc2, bl2, br2, D2, xl2, xr2, NN, 2 * D2, D1);
  k_gat_slot<D2, 16, 2, false, false, true><<<GB, 256, 0, stream>>>(
      se, rowoff, boff, cnti, la, xl2, xr2, We2, att2, bias2, w_ln3, W_out, nullptr, out);
}

// Round 10
// 321.232 us; speedup vs baseline: 1.1068x; 1.1068x over previous
//
#include <hip/hip_runtime.h>
#include <cstddef>

#define NN   30000
#define NNP  30016          /* NN ints rounded to 256B alloc granularity */
#define NE   240000
#define D1   512
#define D2   128
#define NCLS 20
#define NB   ((NN + 255) / 256)   /* 118 scan blocks */

typedef __attribute__((ext_vector_type(8))) short short8;
typedef __attribute__((ext_vector_type(4))) float f32x4;

__device__ __forceinline__ unsigned short f2b(float f) {
  union { float f; unsigned int u; } c; c.f = f;
  unsigned int r = (c.u + 0x7fff + ((c.u >> 16) & 1)) >> 16;  // RNE
  return (unsigned short)r;
}
__device__ __forceinline__ float b2f(unsigned short u) {
  union { unsigned int u; float f; } c; c.u = (unsigned int)u << 16;
  return c.f;
}

// ---------------------------------------------------------------- fused init
#define INIT_TOT 1048048
__global__ __launch_bounds__(256) void k_init(
    const float* __restrict__ x,
    const float* __restrict__ Wl1, const float* __restrict__ Wr1,
    const float* __restrict__ Wl2, const float* __restrict__ Wr2,
    int* __restrict__ zbase,
    unsigned short* __restrict__ xb,
    unsigned short* __restrict__ Wc1, unsigned short* __restrict__ Wc2) {
  int i = blockIdx.x * 256 + threadIdx.x;
  if (i < 22512) { ((int4*)zbase)[i] = make_int4(0, 0, 0, 0); return; }
  const float* in; unsigned short* outp; int off;
  if      (i <  982512) { in = x;   outp = xb;          off = i -   22512; }
  else if (i <  998896) { in = Wl1; outp = Wc1;         off = i -  982512; }
  else if (i < 1015280) { in = Wr1; outp = Wc1 + 65536; off = i -  998896; }
  else if (i < 1031664) { in = Wl2; outp = Wc2;         off = i - 1015280; }
  else if (i < 1048048) { in = Wr2; outp = Wc2 + 65536; off = i - 1031664; }
  else return;
  float4 v = ((const float4*)in)[off];
  ushort4 o;
  o.x = f2b(v.x); o.y = f2b(v.y); o.z = f2b(v.z); o.w = f2b(v.w);
  ((ushort4*)outp)[off] = o;
}

__global__ __launch_bounds__(256) void k_deg(const int* __restrict__ dst,
                                             const float* __restrict__ eattr,
                                             int* __restrict__ cnti,
                                             float* __restrict__ lsum) {
  int e = blockIdx.x * 256 + threadIdx.x;
  if (e < NE) {
    int d = dst[e];
    atomicAdd(&cnti[d], 1);
    atomicAdd(&lsum[d], eattr[e]);
  }
}

// block-scan of degrees + self-loop attr (la) in one pass
__global__ __launch_bounds__(256) void k_scan1(const int* __restrict__ cnti,
                                               const float* __restrict__ lsum,
                                               int* __restrict__ rowoff,
                                               int* __restrict__ bsum,
                                               float* __restrict__ la) {
  int i = blockIdx.x * 256 + threadIdx.x;
  int c = (i < NN) ? cnti[i] : 0;
  if (i < NN) la[i] = lsum[i] / fmaxf((float)c, 1.0f);
  int lane = threadIdx.x & 63, w = threadIdx.x >> 6;
  int v = c;
#pragma unroll
  for (int o = 1; o < 64; o <<= 1) { int t = __shfl_up(v, o); if (lane >= o) v += t; }
  __shared__ int ws[4];
  if (lane == 63) ws[w] = v;
  __syncthreads();
  int add = 0;
  for (int k = 0; k < w; k++) add += ws[k];
  v += add;
  if (i < NN) rowoff[i] = v - c;
  if (threadIdx.x == 255) bsum[blockIdx.x] = v;
}

__global__ __launch_bounds__(128) void k_scan2(const int* __restrict__ bsum,
                                               int* __restrict__ boff) {
  __shared__ int s[128];
  int t = threadIdx.x;
  int orig = (t < NB) ? bsum[t] : 0;
  s[t] = orig;
  __syncthreads();
  for (int o = 1; o < 128; o <<= 1) {
    int v = (t >= o) ? s[t - o] : 0;
    __syncthreads();
    s[t] += v;
    __syncthreads();
  }
  boff[t] = s[t] - orig;
}

__global__ __launch_bounds__(256) void k_fill(const int* __restrict__ src,
                                              const int* __restrict__ dst,
                                              const float* __restrict__ eattr,
                                              const int* __restrict__ rowoff,
                                              const int* __restrict__ boff,
                                              int* __restrict__ cursor,
                                              int2* __restrict__ se) {
  int e = blockIdx.x * 256 + threadIdx.x;
  if (e < NE) {
    int d = dst[e];
    int pos = rowoff[d] + boff[d >> 8] + atomicAdd(&cursor[d], 1);
    se[pos] = make_int2(src[e], __float_as_int(eattr[e]));
  }
}

// ---------------------------------------------------------------- bf16 MFMA GEMM
// [Cl|Cr][m,n] = sum_k A[m,k]*W[n,k] + bias, W = [Wl;Wr] concat in n; split out.
// R7 structure (both operands staged, BK=32); BN templated for occupancy.
template <int BN, int NT>   // NT = BN/32 n-tiles per wave
__global__ __launch_bounds__(256) void gemm_mfma(
    const unsigned short* __restrict__ A, const unsigned short* __restrict__ W,
    const float* __restrict__ bl, const float* __restrict__ br, int Nhalf,
    unsigned short* __restrict__ Cl, unsigned short* __restrict__ Cr,
    int M, int N, int K) {
  constexpr int BM = 128, BK = 32, LDK = BK + 8;
  __shared__ __align__(16) unsigned short As[BM * LDK];
  __shared__ __align__(16) unsigned short Bs[BN * LDK];
  const int bm = blockIdx.y * BM;
  const int bn = blockIdx.x * BN;
  const int tid = threadIdx.x;
  const int wid = tid >> 6, lane = tid & 63;
  const int wm = (wid >> 1) * 64;
  const int wn = (wid & 1) * (NT * 16);
  const int l16 = lane & 15, lq = lane >> 4;
  const int r0 = tid >> 2;
  const int ks = (tid & 3) * 8;

  f32x4 acc[4][NT];
#pragma unroll
  for (int i = 0; i < 4; ++i)
#pragma unroll
    for (int j = 0; j < NT; ++j) acc[i][j] = (f32x4){0.f, 0.f, 0.f, 0.f};

  for (int k0 = 0; k0 < K; k0 += BK) {
#pragma unroll
    for (int p = 0; p < BM / 64; ++p) {
      int r = r0 + p * 64;
      int gm = bm + r;
      uint4 v = {0u, 0u, 0u, 0u};
      if (gm < M) v = *(const uint4*)(A + (size_t)gm * K + k0 + ks);
      *(uint4*)&As[r * LDK + ks] = v;
    }
#pragma unroll
    for (int p = 0; p < BN / 64; ++p) {
      int r = r0 + p * 64;
      int gn = bn + r;
      uint4 v = {0u, 0u, 0u, 0u};
      if (gn < N) v = *(const uint4*)(W + (size_t)gn * K + k0 + ks);
      *(uint4*)&Bs[r * LDK + ks] = v;
    }
    __syncthreads();
    short8 af[4], bfr[NT];
#pragma unroll
    for (int mt = 0; mt < 4; ++mt)
      af[mt] = *(const short8*)&As[(wm + mt * 16 + l16) * LDK + lq * 8];
#pragma unroll
    for (int nt = 0; nt < NT; ++nt)
      bfr[nt] = *(const short8*)&Bs[(wn + nt * 16 + l16) * LDK + lq * 8];
#pragma unroll
    for (int mt = 0; mt < 4; ++mt)
#pragma unroll
      for (int nt = 0; nt < NT; ++nt)
        acc[mt][nt] = __builtin_amdgcn_mfma_f32_16x16x32_bf16(
            af[mt], bfr[nt], acc[mt][nt], 0, 0, 0);
    __syncthreads();
  }

#pragma unroll
  for (int mt = 0; mt < 4; ++mt)
#pragma unroll
    for (int nt = 0; nt < NT; ++nt) {
      int col = bn + wn + nt * 16 + l16;
      bool left = col < Nhalf;                 // uniform: 64-col strips
      int cc = left ? col : col - Nhalf;
      float b = left ? bl[cc] : br[cc];
      unsigned short* Cp = left ? Cl : Cr;
#pragma unroll
      for (int r = 0; r < 4; ++r) {
        int row = bm + wm + mt * 16 + lq * 4 + r;
        if (row < M) Cp[(size_t)row * Nhalf + cc] = f2b(acc[mt][nt][r] + b);
      }
    }
}

// ---------------------------------------------------------------- fused GATv2 aggregate
// R7 structure (best of 5 variants tried): ONE wave per destination node, both
// heads (lanes [0,32)=h0, [32,64)=h1). Per-edge logit: 5-stage half-wave
// butterfly serves both heads at once. 4 edges/iteration, wgt=0 masking.
// Node-uniform state scalarized via readfirstlane. xs stored once (no dual b2f).
template <int D, bool DO_SILU, bool OBF, bool HEAD_GEMM>
__global__ __launch_bounds__(256) void k_gat_node(
    const int2* __restrict__ se,
    const int* __restrict__ rowoff, const int* __restrict__ boff,
    const int* __restrict__ cnti, const float* __restrict__ la,
    const unsigned short* __restrict__ xl, const unsigned short* __restrict__ xr,
    const float* __restrict__ We, const float* __restrict__ att,
    const float* __restrict__ bias, const float* __restrict__ w_ln,
    const float* __restrict__ Wout,
    unsigned short* __restrict__ outb, float* __restrict__ outf) {
  constexpr int VEC = D / 64;      // channels per lane (8 for D1, 2 for D2)
  typedef __attribute__((ext_vector_type(VEC))) unsigned short uvec;
  const int w = __builtin_amdgcn_readfirstlane(threadIdx.x) >> 6;  // SGPR wave id
  const int n = blockIdx.x * 4 + w;                                // SGPR node
  const int lane = threadIdx.x & 63;
  const int c0 = lane * VEC;

  float xd[VEC], we[VEC], at[VEC], acc[VEC] = {};
  {
    uvec u = *(const uvec*)(xr + (size_t)n * D + c0);
#pragma unroll
    for (int k = 0; k < VEC; k++) {
      xd[k] = b2f(u[k]);
      we[k] = We[c0 + k];
      at[k] = att[c0 + k];
    }
  }

  const int start = rowoff[n] + boff[n >> 8];
  const int deg = cnti[n];
  const int total = deg + 1;                    // + self-loop
  const float lan = la[n];
  float denom = 0.f;

  for (int base = 0; base < total; base += 4) {
    int s[4]; float ea[4], wgt[4];
#pragma unroll
    for (int k = 0; k < 4; k++) {
      int idx = base + k;
      if (idx < deg) { int2 e = se[start + idx]; s[k] = e.x; ea[k] = __int_as_float(e.y); }
      else           { s[k] = n; ea[k] = lan; }
      wgt[k] = (idx < total) ? 1.f : 0.f;
    }
    uvec u[4];
#pragma unroll
    for (int k = 0; k < 4; k++)
      u[k] = *(const uvec*)(xl + (size_t)s[k] * D + c0);   // 4 gathers in flight
    float xs[4][VEC];
    float p[4] = {};
#pragma unroll
    for (int k = 0; k < VEC; k++) {
#pragma unroll
      for (int j = 0; j < 4; j++) {
        xs[j][k] = b2f(u[j][k]);
        float q = xs[j][k] + fmaf(ea[j], we[k], xd[k]);
        q = fmaxf(q, 0.2f * q);
        p[j] = fmaf(at[k], q, p[j]);
      }
    }
#pragma unroll
    for (int o = 16; o > 0; o >>= 1) {           // half-wave butterfly, 4 chains
#pragma unroll
      for (int j = 0; j < 4; j++) p[j] += __shfl_xor(p[j], o);
    }
    float pe[4];
#pragma unroll
    for (int j = 0; j < 4; j++) {
      pe[j] = __expf(p[j]) * wgt[j];
      denom += pe[j];
    }
#pragma unroll
    for (int k = 0; k < VEC; k++) {
#pragma unroll
      for (int j = 0; j < 4; j++)
        acc[k] = fmaf(pe[j], xs[j][k], acc[k]);
    }
  }

  float inv = 1.f / denom;                       // per-head (per half-wave)
  float vv[VEC], ss = 0.f;
#pragma unroll
  for (int k = 0; k < VEC; k++) {
    float v = fmaf(acc[k], inv, bias[c0 + k]);
    if (DO_SILU) v = v / (1.f + __expf(-v));
    vv[k] = v;
    ss += v * v;
  }
#pragma unroll
  for (int o = 32; o > 0; o >>= 1) ss += __shfl_xor(ss, o);   // full-wave
  float rinv = rsqrtf(ss / (float)D + 1e-5f);

  __shared__ __align__(16) float hrow[4][D2];
#pragma unroll
  for (int k = 0; k < VEC; k++) {
    float o = vv[k] * rinv * w_ln[c0 + k];
    if (OBF) outb[(size_t)n * D + c0 + k] = f2b(o);
    if (HEAD_GEMM) hrow[w][c0 + k] = o;
  }
  if (HEAD_GEMM) {
    __syncthreads();                             // no early returns: NN % 4 == 0
    int t = threadIdx.x;
    if (t < 4 * NCLS) {
      int n4 = t / NCLS, c = t % NCLS;
      const float4* wr = (const float4*)(Wout + c * D2);
      const float4* hr = (const float4*)&hrow[n4][0];
      float sm = 0.f;
#pragma unroll
      for (int q = 0; q < D2 / 4; q++) {
        float4 a = hr[q], b = wr[q];
        sm += a.x * b.x + a.y * b.y + a.z * b.z + a.w * b.w;
      }
      outf[(size_t)(blockIdx.x * 4 + n4) * NCLS + c] = sm;
    }
  }
}

// ---------------------------------------------------------------- launch
extern "C" void kernel_launch(void* const* d_in, const int* in_sizes, int n_in,
                              void* d_out, int out_size, void* d_ws, size_t ws_size,
                              hipStream_t stream) {
  const float* x     = (const float*)d_in[0];
  const int*   ei    = (const int*)  d_in[1];
  const float* eattr = (const float*)d_in[2];
  const float* Wl1   = (const float*)d_in[3];
  const float* bl1   = (const float*)d_in[4];
  const float* Wr1   = (const float*)d_in[5];
  const float* br1   = (const float*)d_in[6];
  const float* We1   = (const float*)d_in[7];
  const float* att1  = (const float*)d_in[8];
  const float* bias1 = (const float*)d_in[9];
  const float* Wl2   = (const float*)d_in[10];
  const float* bl2   = (const float*)d_in[11];
  const float* Wr2   = (const float*)d_in[12];
  const float* br2   = (const float*)d_in[13];
  const float* We2   = (const float*)d_in[14];
  const float* att2  = (const float*)d_in[15];
  const float* bias2 = (const float*)d_in[16];
  const float* w_ln1 = (const float*)d_in[17];
  const float* w_ln3 = (const float*)d_in[18];
  const float* W_out = (const float*)d_in[19];
  float* out = (float*)d_out;
  (void)in_sizes; (void)n_in; (void)out_size; (void)ws_size;

  const int* src = ei;
  const int* dst = ei + NE;

  char* wsp = (char*)d_ws;
  auto alloc = [&](size_t nbytes) {
    char* ptr = wsp;
    wsp += ((nbytes + 255) / 256) * 256;
    return ptr;
  };
  int*   cnti   = (int*)  alloc((size_t)NN * 4);   // } contiguous (NNP ints each):
  int*   cursor = (int*)  alloc((size_t)NN * 4);   // } zeroed as 3*NNP ints in k_init
  float* lsum   = (float*)alloc((size_t)NN * 4);   // }
  float* la     = (float*)alloc((size_t)NN * 4);
  int*   rowoff = (int*)  alloc((size_t)NN * 4);
  int*   bsum   = (int*)  alloc(128 * 4);
  int*   boff   = (int*)  alloc(128 * 4);
  int2*  se     = (int2*) alloc((size_t)NE * 8);
  unsigned short* xb   = (unsigned short*)alloc((size_t)NN * D2 * 2);
  unsigned short* Wc1  = (unsigned short*)alloc((size_t)2 * D1 * D2 * 2);
  unsigned short* Wc2  = (unsigned short*)alloc((size_t)2 * D2 * D1 * 2);
  unsigned short* xl1  = (unsigned short*)alloc((size_t)NN * D1 * 2);  // gather table
  unsigned short* xr1  = (unsigned short*)alloc((size_t)NN * D1 * 2);
  unsigned short* h1b  = (unsigned short*)alloc((size_t)NN * D1 * 2);
  unsigned short* xl2  = (unsigned short*)alloc((size_t)NN * D2 * 2);
  unsigned short* xr2  = (unsigned short*)alloc((size_t)NN * D2 * 2);

  // --- fused init/cast + CSR build ---
  k_init<<<(INIT_TOT + 255) / 256, 256, 0, stream>>>(x, Wl1, Wr1, Wl2, Wr2,
                                                     cnti, xb, Wc1, Wc2);
  k_deg<<<(NE + 255) / 256, 256, 0, stream>>>(dst, eattr, cnti, lsum);
  k_scan1<<<NB, 256, 0, stream>>>(cnti, lsum, rowoff, bsum, la);
  k_scan2<<<1, 128, 0, stream>>>(bsum, boff);
  k_fill<<<(NE + 255) / 256, 256, 0, stream>>>(src, dst, eattr, rowoff, boff, cursor, se);

  const int GB = NN / 4;             // 4 nodes/block, 1 wave each (NN % 4 == 0)
  const int MB = (NN + 127) / 128;   // 235 row-tiles

  // --- layer 1: [xl1|xr1] = x @ [Wl1;Wr1]^T + [bl1;br1]  (split bf16 out) ---
  gemm_mfma<128, 4><<<dim3(2 * D1 / 128, MB), 256, 0, stream>>>(
      xb, Wc1, bl1, br1, D1, xl1, xr1, NN, 2 * D1, D2);
  k_gat_node<D1, true, true, false><<<GB, 256, 0, stream>>>(
      se, rowoff, boff, cnti, la, xl1, xr1, We1, att1, bias1, w_ln1, nullptr, h1b, nullptr);

  // --- layer 2: [xl2|xr2] = h1 @ [Wl2;Wr2]^T + [bl2;br2]  (split bf16 out) ---
  gemm_mfma<64, 2><<<dim3(2 * D2 / 64, MB), 256, 0, stream>>>(
      h1b, Wc2, bl2, br2, D2, xl2, xr2, NN, 2 * D2, D1);
  k_gat_node<D2, false, false, true><<<GB, 256, 0, stream>>>(
      se, rowoff, boff, cnti, la, xl2, xr2, We2, att2, bias2, w_ln3, W_out, nullptr, out);
}